// Round 1
// 513.460 us; speedup vs baseline: 1.0107x; 1.0107x over previous
//
#include <hip/hip_runtime.h>
#include <math.h>

// Problem constants (HierarchicalAttention: WML=64, B=64, S=40, D=512)
#define BB   64
#define SS   40
#define WMLC 64
#define DD   512
#define NN   2560           // S*WML
#define NBLK 20             // chunks (blocks) per batch for the main pass
#define WPB  4              // waves per block
#define NWAVES (NBLK*WPB)   // 80 waves per batch
#define RPW (NN/NWAVES)     // 32 rows per wave
#define ABLK (NN/256)       // 10 align blocks per batch
#define L2E 1.4426950408889634f

__device__ __forceinline__ float wave_reduce_sum(float v) {
    // butterfly across all 64 lanes; every lane ends with the total
    #pragma unroll
    for (int off = 32; off > 0; off >>= 1) v += __shfl_xor(v, off, 64);
    return v;
}

// ---------------------------------------------------------------------------
// K1: fused projections + sentence scores.
// grid (2, B): x=0 -> qw = source @ W_word^T (to global).
//              x=1 -> qs = source @ W_sent^T (kept in LDS only), then
//                     sstat[b,s] = dot(qs, sent_bank[s,b,:]) * static_attn[b,s].
// 256 thr; thread t does rows d=t and d=t+256 of W (row-major (D,D)).
// ---------------------------------------------------------------------------
__global__ __launch_bounds__(256) void k_proj(const float* __restrict__ src,
                                              const float* __restrict__ Ww,
                                              const float* __restrict__ Ws,
                                              const float* __restrict__ sb,
                                              const float* __restrict__ sa,
                                              float* __restrict__ qw,
                                              float* __restrict__ sstat) {
    __shared__ float xs[DD];
    __shared__ float qsl[DD];
    const int b = blockIdx.y;
    const int t = threadIdx.x;
    const bool sent = blockIdx.x != 0;
    const float* W = sent ? Ws : Ww;
    ((float2*)xs)[t] = ((const float2*)(src + b * DD))[t];
    __syncthreads();
    const float* r0 = W + (size_t)t * DD;
    const float* r1 = W + (size_t)(t + 256) * DD;
    float acc0 = 0.f, acc1 = 0.f;
    for (int k = 0; k < DD; k += 4) {
        float4 x  = *(const float4*)(xs + k);
        float4 w0 = *(const float4*)(r0 + k);
        float4 w1 = *(const float4*)(r1 + k);
        acc0 += x.x * w0.x + x.y * w0.y + x.z * w0.z + x.w * w0.w;
        acc1 += x.x * w1.x + x.y * w1.y + x.z * w1.z + x.w * w1.w;
    }
    if (!sent) {
        qw[b * DD + t] = acc0;
        qw[b * DD + t + 256] = acc1;
        return;
    }
    // sentence path: qs stays in LDS, then 40 sentence dots (10 per wave)
    qsl[t] = acc0;
    qsl[t + 256] = acc1;
    __syncthreads();
    const int wave = t >> 6, lane = t & 63;
    const int d0 = lane * 4, d1 = 256 + lane * 4;
    const float4 q0 = *(const float4*)(qsl + d0);
    const float4 q1 = *(const float4*)(qsl + d1);
    for (int j = 0; j < SS / WPB; ++j) {
        const int s = wave * (SS / WPB) + j;
        const float* row = sb + ((size_t)s * BB + b) * DD;
        float4 a0 = *(const float4*)(row + d0);
        float4 a1 = *(const float4*)(row + d1);
        float p = a0.x * q0.x + a0.y * q0.y + a0.z * q0.z + a0.w * q0.w
                + a1.x * q1.x + a1.y * q1.y + a1.z * q1.z + a1.w * q1.w;
        p = wave_reduce_sum(p);
        if (lane == 0) sstat[b * SS + s] = p * sa[b * SS + s];
    }
}

// ---------------------------------------------------------------------------
// K2 (main, HBM-bound): single streaming pass over the VALID rows of
// word_bank. One wave owns rows n = gw + 80k (k<32), all within batch b.
// 1-deep register prefetch: the next valid row's loads are issued BEFORE
// the wave-reduce/softmax chain of the current row, so a load stays in
// flight across the serial part (compiler emits s_waitcnt vmcnt(2)).
// wl/sstat rows cached in LDS once per block (wave-uniform broadcast reads).
// ---------------------------------------------------------------------------
#define PROCESS_ROW()                                                          \
    {                                                                          \
        float p = p0.x * qa0.x + p0.y * qa0.y + p0.z * qa0.z + p0.w * qa0.w    \
                + p1.x * qa1.x + p1.y * qa1.y + p1.z * qa1.z + p1.w * qa1.w;   \
        p = wave_reduce_sum(p);                                                \
        const float a = p * s_st[pn >> 6];                                     \
        if (lane == 0) scores[b * NN + pn] = a;                                \
        if (a > m) {                                                           \
            const float sc = (m == -INFINITY) ? 0.f : exp2f((m - a) * L2E);    \
            l *= sc;                                                           \
            c0.x *= sc; c0.y *= sc; c0.z *= sc; c0.w *= sc;                    \
            c1.x *= sc; c1.y *= sc; c1.z *= sc; c1.w *= sc;                    \
            m = a;                                                             \
        }                                                                      \
        const float e = exp2f((a - m) * L2E);                                  \
        l += e;                                                                \
        c0.x += e * p0.x; c0.y += e * p0.y; c0.z += e * p0.z; c0.w += e * p0.w;\
        c1.x += e * p1.x; c1.y += e * p1.y; c1.z += e * p1.z; c1.w += e * p1.w;\
    }

__global__ __launch_bounds__(256) void k_main(const float* __restrict__ wb,
                                              const float* __restrict__ qw,
                                              const float* __restrict__ sstat,
                                              const int* __restrict__ wl,
                                              float* __restrict__ scores,
                                              float* __restrict__ part_c,
                                              float* __restrict__ part_ml) {
    __shared__ int   s_wl[SS];
    __shared__ float s_st[SS];
    __shared__ float s_m[WPB], s_l[WPB];
    __shared__ float s_c[WPB][DD];
    const int b = blockIdx.y;
    const int chunk = blockIdx.x;
    const int t = threadIdx.x, wave = t >> 6, lane = t & 63;
    if (t < SS) {
        s_wl[t] = wl[b * SS + t];
        s_st[t] = sstat[b * SS + t];
    }
    const int gw = chunk * WPB + wave;               // 0..79
    const int d0 = lane * 4, d1 = 256 + lane * 4;
    const float4 qa0 = *(const float4*)(qw + b * DD + d0);
    const float4 qa1 = *(const float4*)(qw + b * DD + d1);
    __syncthreads();

    float m = -INFINITY, l = 0.f;
    float4 c0 = {0.f, 0.f, 0.f, 0.f}, c1 = {0.f, 0.f, 0.f, 0.f};

    int    pn = -1;
    float4 p0 = {0.f, 0.f, 0.f, 0.f}, p1 = {0.f, 0.f, 0.f, 0.f};

    int k = 0;
    // prologue: find + load first valid row
    for (; k < RPW; ++k) {
        const int n = gw + k * NWAVES;
        const int s = n >> 6, w = n & 63;
        if (w < s_wl[s]) {
            const float* row = wb + (size_t)((w * BB + b) * SS + s) * DD;
            p0 = *(const float4*)(row + d0);
            p1 = *(const float4*)(row + d1);
            pn = n;
            ++k;
            break;
        }
    }
    // steady state: issue next load, then process the prefetched row
    for (; k < RPW; ++k) {
        const int n = gw + k * NWAVES;
        const int s = n >> 6, w = n & 63;
        if (w >= s_wl[s]) continue;                  // wave-uniform skip, no load
        const float* row = wb + (size_t)((w * BB + b) * SS + s) * DD;
        const float4 f0 = *(const float4*)(row + d0);
        const float4 f1 = *(const float4*)(row + d1);
        PROCESS_ROW();
        p0 = f0; p1 = f1; pn = n;
    }
    if (pn >= 0) PROCESS_ROW();

    // intra-block combine of the 4 wave partials
    *(float4*)(&s_c[wave][d0]) = c0;
    *(float4*)(&s_c[wave][d1]) = c1;
    if (lane == 0) { s_m[wave] = m; s_l[wave] = l; }
    __syncthreads();
    const float mb = fmaxf(fmaxf(s_m[0], s_m[1]), fmaxf(s_m[2], s_m[3]));
    float lb = 0.f, cA = 0.f, cB = 0.f;
    #pragma unroll
    for (int wv = 0; wv < WPB; ++wv) {
        const float mi = s_m[wv];
        const float sc = (mi == -INFINITY) ? 0.f : exp2f((mi - mb) * L2E);
        lb += s_l[wv] * sc;
        cA += s_c[wv][t] * sc;
        cB += s_c[wv][t + 256] * sc;
    }
    const int pidx = b * NBLK + chunk;
    part_c[(size_t)pidx * DD + t] = cA;
    part_c[(size_t)pidx * DD + t + 256] = cB;
    if (t == 0) { part_ml[pidx * 2] = mb; part_ml[pidx * 2 + 1] = lb; }
}

// ---------------------------------------------------------------------------
// K3: per-batch reduction of the NBLK partials -> c_final[b,:], m_g, 1/Z
// ---------------------------------------------------------------------------
__global__ __launch_bounds__(256) void k_reduce(const float* __restrict__ part_c,
                                                const float* __restrict__ part_ml,
                                                float* __restrict__ c_final,
                                                float* __restrict__ mz) {
    const int b = blockIdx.x, t = threadIdx.x;
    float mg = -INFINITY;
    for (int i = 0; i < NBLK; ++i) mg = fmaxf(mg, part_ml[(b * NBLK + i) * 2]);
    float Z = 0.f, cA = 0.f, cB = 0.f;
    for (int i = 0; i < NBLK; ++i) {
        const float mi = part_ml[(b * NBLK + i) * 2];
        const float li = part_ml[(b * NBLK + i) * 2 + 1];
        const float sc = (mi == -INFINITY) ? 0.f : exp2f((mi - mg) * L2E);
        Z += li * sc;
        cA += part_c[(size_t)(b * NBLK + i) * DD + t] * sc;
        cB += part_c[(size_t)(b * NBLK + i) * DD + t + 256] * sc;
    }
    const float invZ = 1.0f / Z;   // Z>0: every sentence has >=1 valid word
    c_final[b * DD + t] = cA * invZ;
    c_final[b * DD + t + 256] = cB * invZ;
    if (t == 0) { mz[b * 2] = mg; mz[b * 2 + 1] = invZ; }
}

// ---------------------------------------------------------------------------
// K4: fused finalize. grid (ABLK+2, B):
//   x <  ABLK : align_vectors finalized IN PLACE over the raw-score region:
//               valid -> exp(a - m_g)/Z + 1e-20 ; masked -> 1e-20 exactly.
//   x >= ABLK : attn_h[b,d] = tanh(sum_k concat(c,source)[b,k] * W_out[d,k]),
//               d = (x-ABLK)*256 + t.
// Both roles depend only on K3 outputs -> one launch.
// ---------------------------------------------------------------------------
__global__ __launch_bounds__(256) void k_fin(const int* __restrict__ wl,
                                             const float* __restrict__ mz,
                                             float* __restrict__ av,
                                             const float* __restrict__ c_final,
                                             const float* __restrict__ src,
                                             const float* __restrict__ Wout,
                                             float* __restrict__ out) {
    __shared__ float xs[2 * DD];
    const int b = blockIdx.y;
    const int t = threadIdx.x;
    if (blockIdx.x < ABLK) {
        const int n = blockIdx.x * 256 + t;
        const int s = n >> 6, w = n & 63;
        const int len = wl[b * SS + s];
        float v = 1e-20f;
        if (w < len) {
            const float a = av[b * NN + n];
            v = exp2f((a - mz[b * 2]) * L2E) * mz[b * 2 + 1] + 1e-20f;
        }
        av[b * NN + n] = v;
        return;
    }
    ((float2*)xs)[t] = ((const float2*)(c_final + b * DD))[t];
    ((float2*)(xs + DD))[t] = ((const float2*)(src + b * DD))[t];
    __syncthreads();
    const int d = (blockIdx.x - ABLK) * 256 + t;
    const float* row = Wout + (size_t)d * (2 * DD);
    float acc = 0.f;
    for (int k = 0; k < 2 * DD; k += 4) {
        float4 x = *(const float4*)(xs + k);
        float4 w = *(const float4*)(row + k);
        acc += x.x * w.x + x.y * w.y + x.z * w.z + x.w * w.w;
    }
    out[b * DD + d] = tanhf(acc);
}

// ---------------------------------------------------------------------------
extern "C" void kernel_launch(void* const* d_in, const int* in_sizes, int n_in,
                              void* d_out, int out_size, void* d_ws, size_t ws_size,
                              hipStream_t stream) {
    const float* src = (const float*)d_in[0];   // [B, D]
    const float* wb  = (const float*)d_in[1];   // [WML, B, S, D]
    const int*   wl  = (const int*)  d_in[2];   // [B, S]
    const float* sb  = (const float*)d_in[3];   // [S, B, D]
    /* d_in[4] = sent_lengths: unused by forward math */
    const float* sa  = (const float*)d_in[5];   // [B, S]
    const float* Ww  = (const float*)d_in[6];   // [D, D]
    const float* Wsn = (const float*)d_in[7];   // [D, D]
    const float* Wo  = (const float*)d_in[8];   // [D, 2D]
    float* out = (float*)d_out;                 // [B*D] attn_h, then [B*N] align

    float* ws = (float*)d_ws;
    float* qw      = ws;                        // 32768
    float* sstat   = ws + 32768;                // 2560
    float* part_c  = ws + 35328;                // 64*20*512 = 655360
    float* part_ml = ws + 690688;               // 64*20*2   = 2560
    float* mz      = ws + 693248;               // 128
    float* c_final = ws + 693376;               // 32768  (end: 726144 floats ~= 2.9 MB)

    float* scores = out + BB * DD;              // raw scores live in the align slot

    hipLaunchKernelGGL(k_proj,   dim3(2, BB),        dim3(256), 0, stream,
                       src, Ww, Wsn, sb, sa, qw, sstat);
    hipLaunchKernelGGL(k_main,   dim3(NBLK, BB),     dim3(256), 0, stream,
                       wb, qw, sstat, wl, scores, part_c, part_ml);
    hipLaunchKernelGGL(k_reduce, dim3(BB),           dim3(256), 0, stream,
                       part_c, part_ml, c_final, mz);
    hipLaunchKernelGGL(k_fin,    dim3(ABLK + 2, BB), dim3(256), 0, stream,
                       wl, mz, scores, c_final, src, Wo, out);
}

// Round 2
// 487.006 us; speedup vs baseline: 1.0656x; 1.0543x over previous
//
#include <hip/hip_runtime.h>
#include <math.h>

// Problem constants (HierarchicalAttention: WML=64, B=64, S=40, D=512)
#define BB   64
#define SS   40
#define WMLC 64
#define DD   512
#define NN   2560           // S*WML
#define NBLK 20             // chunks (blocks) per batch for the main pass
#define WPB  4              // waves per block
#define NWAVES (NBLK*WPB)   // 80 waves per batch
#define RPW (NN/NWAVES)     // 32 rows per wave
#define ABLK (NN/256)       // 10 align blocks per batch
#define HBLK 8              // attn_h blocks per batch (64 outputs each)
#define L2E 1.4426950408889634f

__device__ __forceinline__ float wave_reduce_sum(float v) {
    // butterfly across all 64 lanes; every lane ends with the total
    #pragma unroll
    for (int off = 32; off > 0; off >>= 1) v += __shfl_xor(v, off, 64);
    return v;
}

// ---------------------------------------------------------------------------
// K1: fused projections + sentence-score partials. grid (8, B), 256 thr.
//   x in 0..3: word path, d-chunk x: qw[b, x*128 + j] for j<128.
//              2 threads per output row, split-K halves, shfl_xor(1) combine.
//   x in 4..7: sent path, d-chunk (x-4): q_s chunk (128 vals) kept in LDS,
//              then 40 sentence PARTIAL dots over this d-range ->
//              sstat_part[(b*S+s)*4 + chunk]. (sa multiply happens in K2.)
// Rationale: old grid (2,B)=128 blocks left half the CUs idle and pushed
// 1 MB of W through one CU per block (~8 us). Now 512 blocks, 256 KB each.
// ---------------------------------------------------------------------------
__global__ __launch_bounds__(256) void k_proj(const float* __restrict__ src,
                                              const float* __restrict__ Ww,
                                              const float* __restrict__ Ws,
                                              const float* __restrict__ sb,
                                              float* __restrict__ qw,
                                              float* __restrict__ sstat_part) {
    __shared__ float xs[DD];
    __shared__ float qsl[128];
    const int b = blockIdx.y;
    const int t = threadIdx.x;
    const bool sent = blockIdx.x >= 4;
    const int chunk = sent ? (blockIdx.x - 4) : blockIdx.x;
    const float* W = sent ? Ws : Ww;
    ((float2*)xs)[t] = ((const float2*)(src + b * DD))[t];
    __syncthreads();

    // q chunk: output row d, K-half per thread, combine across lane pairs
    const int j = t >> 1, half = t & 1;
    const int d = chunk * 128 + j;
    const float* r = W + (size_t)d * DD + half * 256;
    const float* x = xs + half * 256;
    float acc = 0.f;
    for (int k = 0; k < 256; k += 4) {
        float4 xv = *(const float4*)(x + k);
        float4 wv = *(const float4*)(r + k);
        acc += xv.x * wv.x + xv.y * wv.y + xv.z * wv.z + xv.w * wv.w;
    }
    acc += __shfl_xor(acc, 1, 64);

    if (!sent) {
        if (half == 0) qw[b * DD + d] = acc;
        return;
    }
    if (half == 0) qsl[j] = acc;
    __syncthreads();

    // sentence partial dots over this 128-d chunk; 10 sentences per wave
    const int wave = t >> 6, lane = t & 63;
    const float2 q = *(const float2*)(qsl + lane * 2);
    for (int jj = 0; jj < SS / WPB; ++jj) {
        const int s = wave * (SS / WPB) + jj;
        const float* row = sb + ((size_t)s * BB + b) * DD + chunk * 128;
        float2 a = *(const float2*)(row + lane * 2);
        float p = a.x * q.x + a.y * q.y;
        p = wave_reduce_sum(p);
        if (lane == 0) sstat_part[(b * SS + s) * 4 + chunk] = p;
    }
}

// ---------------------------------------------------------------------------
// K2 (main, HBM-bound): single streaming pass over the VALID rows of
// word_bank. One wave owns rows n = gw + 80k (k<32), all within batch b.
// 1-deep register prefetch keeps a load in flight across the serial
// reduce/softmax chain. wl + summed sstat partials cached in LDS per block.
// ---------------------------------------------------------------------------
#define PROCESS_ROW()                                                          \
    {                                                                          \
        float p = p0.x * qa0.x + p0.y * qa0.y + p0.z * qa0.z + p0.w * qa0.w    \
                + p1.x * qa1.x + p1.y * qa1.y + p1.z * qa1.z + p1.w * qa1.w;   \
        p = wave_reduce_sum(p);                                                \
        const float a = p * s_st[pn >> 6];                                     \
        if (lane == 0) scores[b * NN + pn] = a;                                \
        if (a > m) {                                                           \
            const float sc = (m == -INFINITY) ? 0.f : exp2f((m - a) * L2E);    \
            l *= sc;                                                           \
            c0.x *= sc; c0.y *= sc; c0.z *= sc; c0.w *= sc;                    \
            c1.x *= sc; c1.y *= sc; c1.z *= sc; c1.w *= sc;                    \
            m = a;                                                             \
        }                                                                      \
        const float e = exp2f((a - m) * L2E);                                  \
        l += e;                                                                \
        c0.x += e * p0.x; c0.y += e * p0.y; c0.z += e * p0.z; c0.w += e * p0.w;\
        c1.x += e * p1.x; c1.y += e * p1.y; c1.z += e * p1.z; c1.w += e * p1.w;\
    }

__global__ __launch_bounds__(256) void k_main(const float* __restrict__ wb,
                                              const float* __restrict__ qw,
                                              const float* __restrict__ sstat_part,
                                              const float* __restrict__ sa,
                                              const int* __restrict__ wl,
                                              float* __restrict__ scores,
                                              float* __restrict__ part_c,
                                              float* __restrict__ part_ml) {
    __shared__ int   s_wl[SS];
    __shared__ float s_st[SS];
    __shared__ float s_m[WPB], s_l[WPB];
    __shared__ float s_c[WPB][DD];
    const int b = blockIdx.y;
    const int chunk = blockIdx.x;
    const int t = threadIdx.x, wave = t >> 6, lane = t & 63;
    if (t < SS) {
        s_wl[t] = wl[b * SS + t];
        const float4 pp = *(const float4*)(sstat_part + (b * SS + t) * 4);
        s_st[t] = (pp.x + pp.y + pp.z + pp.w) * sa[b * SS + t];
    }
    const int gw = chunk * WPB + wave;               // 0..79
    const int d0 = lane * 4, d1 = 256 + lane * 4;
    const float4 qa0 = *(const float4*)(qw + b * DD + d0);
    const float4 qa1 = *(const float4*)(qw + b * DD + d1);
    __syncthreads();

    float m = -INFINITY, l = 0.f;
    float4 c0 = {0.f, 0.f, 0.f, 0.f}, c1 = {0.f, 0.f, 0.f, 0.f};

    int    pn = -1;
    float4 p0 = {0.f, 0.f, 0.f, 0.f}, p1 = {0.f, 0.f, 0.f, 0.f};

    int k = 0;
    // prologue: find + load first valid row
    for (; k < RPW; ++k) {
        const int n = gw + k * NWAVES;
        const int s = n >> 6, w = n & 63;
        if (w < s_wl[s]) {
            const float* row = wb + (size_t)((w * BB + b) * SS + s) * DD;
            p0 = *(const float4*)(row + d0);
            p1 = *(const float4*)(row + d1);
            pn = n;
            ++k;
            break;
        }
    }
    // steady state: issue next load, then process the prefetched row
    for (; k < RPW; ++k) {
        const int n = gw + k * NWAVES;
        const int s = n >> 6, w = n & 63;
        if (w >= s_wl[s]) continue;                  // wave-uniform skip, no load
        const float* row = wb + (size_t)((w * BB + b) * SS + s) * DD;
        const float4 f0 = *(const float4*)(row + d0);
        const float4 f1 = *(const float4*)(row + d1);
        PROCESS_ROW();
        p0 = f0; p1 = f1; pn = n;
    }
    if (pn >= 0) PROCESS_ROW();

    // intra-block combine of the 4 wave partials
    *(float4*)(&s_c[wave][d0]) = c0;
    *(float4*)(&s_c[wave][d1]) = c1;
    if (lane == 0) { s_m[wave] = m; s_l[wave] = l; }
    __syncthreads();
    const float mb = fmaxf(fmaxf(s_m[0], s_m[1]), fmaxf(s_m[2], s_m[3]));
    float lb = 0.f, cA = 0.f, cB = 0.f;
    #pragma unroll
    for (int wv = 0; wv < WPB; ++wv) {
        const float mi = s_m[wv];
        const float sc = (mi == -INFINITY) ? 0.f : exp2f((mi - mb) * L2E);
        lb += s_l[wv] * sc;
        cA += s_c[wv][t] * sc;
        cB += s_c[wv][t + 256] * sc;
    }
    const int pidx = b * NBLK + chunk;
    part_c[(size_t)pidx * DD + t] = cA;
    part_c[(size_t)pidx * DD + t + 256] = cB;
    if (t == 0) { part_ml[pidx * 2] = mb; part_ml[pidx * 2 + 1] = lb; }
}

// ---------------------------------------------------------------------------
// K3: fused finalize (k_reduce folded in). grid (ABLK + HBLK, B):
//   x < ABLK : align vectors finalized IN PLACE over the raw-score region.
//              (m_g, 1/Z) recomputed inline from the 160 B part_ml row —
//              uniform scalar loads, cheaper than a dedicated kernel+launch.
//   x >= ABLK: attn_h. Block reduces c_final[b,:] into LDS itself from
//              part_c (40 KB L2 reads), then 64 outputs, 4 threads/output
//              split-K with shfl combine.
// ---------------------------------------------------------------------------
__global__ __launch_bounds__(256) void k_fin(const int* __restrict__ wl,
                                             const float* __restrict__ part_c,
                                             const float* __restrict__ part_ml,
                                             float* __restrict__ av,
                                             const float* __restrict__ src,
                                             const float* __restrict__ Wout,
                                             float* __restrict__ out) {
    __shared__ float xs[2 * DD];
    const int b = blockIdx.y;
    const int t = threadIdx.x;

    // (m_g, 1/Z) from part_ml — uniform addresses, scalarizable
    float mg = -INFINITY;
    #pragma unroll
    for (int i = 0; i < NBLK; ++i)
        mg = fmaxf(mg, part_ml[(b * NBLK + i) * 2]);
    float Z = 0.f;
    float sc[NBLK];
    #pragma unroll
    for (int i = 0; i < NBLK; ++i) {
        const float mi = part_ml[(b * NBLK + i) * 2];
        const float li = part_ml[(b * NBLK + i) * 2 + 1];
        sc[i] = (mi == -INFINITY) ? 0.f : exp2f((mi - mg) * L2E);
        Z += li * sc[i];
    }
    const float invZ = 1.0f / Z;   // Z>0: every sentence has >=1 valid word

    if (blockIdx.x < ABLK) {
        const int n = blockIdx.x * 256 + t;
        const int s = n >> 6, w = n & 63;
        const int len = wl[b * SS + s];
        float v = 1e-20f;
        if (w < len) {
            const float a = av[b * NN + n];
            v = exp2f((a - mg) * L2E) * invZ + 1e-20f;
        }
        av[b * NN + n] = v;
        return;
    }

    // attn_h path: reduce c_final[b,:] into LDS (thread t owns elems t, t+256)
    float cA = 0.f, cB = 0.f;
    #pragma unroll
    for (int i = 0; i < NBLK; ++i) {
        cA += part_c[(size_t)(b * NBLK + i) * DD + t] * sc[i];
        cB += part_c[(size_t)(b * NBLK + i) * DD + t + 256] * sc[i];
    }
    xs[t] = cA * invZ;
    xs[t + 256] = cB * invZ;
    ((float2*)(xs + DD))[t] = ((const float2*)(src + b * DD))[t];
    __syncthreads();

    // 64 outputs, 4 threads per output (K quarters), shfl_xor(1,2) combine
    const int j = t >> 2, quarter = t & 3;
    const int d = (blockIdx.x - ABLK) * 64 + j;
    const float* row = Wout + (size_t)d * (2 * DD) + quarter * 256;
    const float* x = xs + quarter * 256;
    float acc = 0.f;
    for (int k = 0; k < 256; k += 4) {
        float4 xv = *(const float4*)(x + k);
        float4 wv = *(const float4*)(row + k);
        acc += xv.x * wv.x + xv.y * wv.y + xv.z * wv.z + xv.w * wv.w;
    }
    acc += __shfl_xor(acc, 1, 64);
    acc += __shfl_xor(acc, 2, 64);
    if (quarter == 0) out[b * DD + d] = tanhf(acc);
}

// ---------------------------------------------------------------------------
extern "C" void kernel_launch(void* const* d_in, const int* in_sizes, int n_in,
                              void* d_out, int out_size, void* d_ws, size_t ws_size,
                              hipStream_t stream) {
    const float* src = (const float*)d_in[0];   // [B, D]
    const float* wb  = (const float*)d_in[1];   // [WML, B, S, D]
    const int*   wl  = (const int*)  d_in[2];   // [B, S]
    const float* sb  = (const float*)d_in[3];   // [S, B, D]
    /* d_in[4] = sent_lengths: unused by forward math */
    const float* sa  = (const float*)d_in[5];   // [B, S]
    const float* Ww  = (const float*)d_in[6];   // [D, D]
    const float* Wsn = (const float*)d_in[7];   // [D, D]
    const float* Wo  = (const float*)d_in[8];   // [D, 2D]
    float* out = (float*)d_out;                 // [B*D] attn_h, then [B*N] align

    float* ws = (float*)d_ws;
    float* qw         = ws;                     // 32768
    float* sstat_part = ws + 32768;             // 64*40*4 = 10240
    float* part_c     = ws + 43008;             // 64*20*512 = 655360
    float* part_ml    = ws + 698368;            // 64*20*2   = 2560  (end ~2.8 MB)

    float* scores = out + BB * DD;              // raw scores live in the align slot

    hipLaunchKernelGGL(k_proj, dim3(8, BB),           dim3(256), 0, stream,
                       src, Ww, Wsn, sb, qw, sstat_part);
    hipLaunchKernelGGL(k_main, dim3(NBLK, BB),        dim3(256), 0, stream,
                       wb, qw, sstat_part, sa, wl, scores, part_c, part_ml);
    hipLaunchKernelGGL(k_fin,  dim3(ABLK + HBLK, BB), dim3(256), 0, stream,
                       wl, part_c, part_ml, scores, src, Wo, out);
}